// Round 3
// baseline (1092.416 us; speedup 1.0000x reference)
//
#include <hip/hip_runtime.h>

#define HID   128
#define SEQL  512
#define MT    16
#define TPB   512
#define BATCH 1024

typedef __attribute__((ext_vector_type(4))) float    f32x4;
typedef __attribute__((ext_vector_type(8))) _Float16 f16x8;

union Pack8 { int2 p2[2]; int4 p4; f16x8 h; _Float16 hf[8]; short s[8]; };

__device__ __forceinline__ short f2hs(float f) {
    _Float16 v = (_Float16)f;
    return __builtin_bit_cast(short, v);
}
// inf-safe fast sigmoid/tanh (exp overflow gives correct saturation limits)
__device__ __forceinline__ float fsig(float x) {
    return __builtin_amdgcn_rcpf(1.f + __expf(-x));
}
__device__ __forceinline__ float ftanh(float x) {
    return 1.f - 2.f * __builtin_amdgcn_rcpf(1.f + __expf(2.f * x));
}

// Repack weights into per-lane MFMA B-fragment layout (fp16), sum biases.
// 16x16x32 operand layout: lane l holds col = l&15, elem i -> k = kk*32 + 8*(l>>4) + i.
// A-frags are built with the identical map, so any consistent k-permutation cancels.
__global__ void prep_kernel(const float* __restrict__ w_ih0, const float* __restrict__ w_hh0,
                            const float* __restrict__ b_ih0, const float* __restrict__ b_hh0,
                            const float* __restrict__ w_ih1, const float* __restrict__ w_hh1,
                            const float* __restrict__ b_ih1, const float* __restrict__ b_hh1,
                            short* __restrict__ recW0, short* __restrict__ recW1,
                            short* __restrict__ inW1, short* __restrict__ xW0,
                            float* __restrict__ bias0, float* __restrict__ bias1) {
    int tid = blockIdx.x * 256 + threadIdx.x;
    if (tid < 24576) {                      // 3 matrices of [8w][4g][4kk][64lane][8]
        int m = tid >> 13;
        int r = tid & 8191;
        int lane = r & 63, kk = (r >> 6) & 3, g = (r >> 8) & 3, w = r >> 10;
        int c = lane & 15, g4 = lane >> 4;
        int col = g * 128 + w * 16 + c;
        const float* src = (m == 0) ? w_hh0 : (m == 1) ? w_hh1 : w_ih1;
        short* dst = ((m == 0) ? recW0 : (m == 1) ? recW1 : inW1) + (size_t)r * 8;
        #pragma unroll
        for (int i = 0; i < 8; ++i)
            dst[i] = f2hs(src[col * 128 + kk * 32 + 8 * g4 + i]);
    } else if (tid < 26624) {               // xW0: [8w][4g][64lane][8], K=32
        int r = tid - 24576;
        int lane = r & 63, g = (r >> 6) & 3, w = r >> 8;
        int c = lane & 15, g4 = lane >> 4;
        int col = g * 128 + w * 16 + c;
        short* dst = xW0 + (size_t)r * 8;
        #pragma unroll
        for (int i = 0; i < 8; ++i)
            dst[i] = f2hs(w_ih0[col * 32 + 8 * g4 + i]);
    } else if (tid < 27136) {
        int j = tid - 26624;
        bias0[j] = b_ih0[j] + b_hh0[j];
    } else if (tid < 27648) {
        int j = tid - 27136;
        bias1[j] = b_ih1[j] + b_hh1[j];
    }
}

// Fused 2-layer LSTM: one block = 16 batch rows, 513 iterations.
// Iter t: L0 computes h0(t) (t<512); L1 computes h1(t-1) (t>=1) consuming
// h0(t-1) = hS0[rb] -- the SAME LDS A-fragment L0's recurrent term reads.
// Wave w owns units [16w,16w+16) in all 4 gate regions for BOTH layers ->
// c/h updates lane-local (D-layout col=lane&15, row=4*(lane>>4)+reg).
// Weights: recW0/recW1/xW0 in VGPRs (144/thread); inW1 in LDS (128 KB).
// h state double-buffered fp16 in LDS, 16B-granular XOR swizzle; one
// barrier per iteration.
__global__ __launch_bounds__(TPB, 2) void fused_lstm_kernel(
    const float* __restrict__ x,
    const short* __restrict__ recW0g, const short* __restrict__ recW1g,
    const short* __restrict__ inW1g,  const short* __restrict__ xW0g,
    const float* __restrict__ bias0,  const float* __restrict__ bias1,
    const float* __restrict__ fc1_w, const float* __restrict__ fc1_b,
    const float* __restrict__ fc2_w, const float* __restrict__ fc2_b,
    float* __restrict__ out)
{
    extern __shared__ char smem[];
    short* inL = (short*)smem;                   // 128 KB: inW1 B-frags
    char*  hS0 = smem + 131072;                  // 2 x 4 KB fp16 h0 state
    char*  hS1 = smem + 139264;                  // 2 x 4 KB fp16 h1 state
    // after the loop (and a barrier), smem base is reused: lastH f32[16][128], fcbuf f32[16][64]

    const int tid = threadIdx.x;
    const int w = tid >> 6, lane = tid & 63;
    const int c = lane & 15, g4 = lane >> 4;
    const int row0 = blockIdx.x * MT;

    // stage inW1 into LDS (16384 int4)
    #pragma unroll
    for (int i = 0; i < 32; ++i)
        ((int4*)inL)[i * TPB + tid] = ((const int4*)inW1g)[i * TPB + tid];
    // zero both h-state double buffers (4096 ints)
    #pragma unroll
    for (int i = 0; i < 8; ++i)
        ((int*)hS0)[i * TPB + tid] = 0;

    // loop-invariant register weights
    Pack8 recW0f[4][4], recW1f[4][4], xWf[4];
    #pragma unroll
    for (int g = 0; g < 4; ++g)
        #pragma unroll
        for (int kk = 0; kk < 4; ++kk) {
            recW0f[g][kk].p4 = *(const int4*)(recW0g + (size_t)((((w*4+g)*4+kk)*64 + lane) * 8));
            recW1f[g][kk].p4 = *(const int4*)(recW1g + (size_t)((((w*4+g)*4+kk)*64 + lane) * 8));
        }
    #pragma unroll
    for (int g = 0; g < 4; ++g)
        xWf[g].p4 = *(const int4*)(xW0g + (size_t)(((w*4+g)*64 + lane) * 8));

    float biasr0[4], biasr1[4];
    #pragma unroll
    for (int g = 0; g < 4; ++g) {
        biasr0[g] = bias0[g*128 + w*16 + c];
        biasr1[g] = bias1[g*128 + w*16 + c];
    }

    __syncthreads();

    float cst0[4] = {0.f, 0.f, 0.f, 0.f};
    float cst1[4] = {0.f, 0.f, 0.f, 0.f};

    const float* xp = x + (size_t)(row0 + c) * SEQL * 32 + 8 * g4;
    f32x4 xa = *(const f32x4*)(xp);
    f32x4 xb = *(const f32x4*)(xp + 4);

    const int swz   = (c & 14) << 3;       // 16B-granular XOR swizzle (bits 4-6)
    const int rbase = c * 256;             // A-frag row = batch row c
    const int unit  = w * 16 + c;
    // per-thread LDS write offsets for the 4 D-rows (row = 4*g4+r)
    int woff[4];
    #pragma unroll
    for (int r = 0; r < 4; ++r) {
        int rrow = 4 * g4 + r;
        woff[r] = rrow * 256 + ((unit * 2) ^ ((rrow & 14) << 3));
    }
    const int inBbase = w * 16384;         // bytes: wave's inW1 region in LDS

    for (int t = 0; t <= SEQL; ++t) {
        const int rb = t & 1;
        const char* h0r = hS0 + rb * 4096;
        const char* h1r = hS1 + rb * 4096;
        char* h0w = hS0 + (rb ^ 1) * 4096;
        char* h1w = hS1 + (rb ^ 1) * 4096;

        // A-frags of h0(t-1): feed L0-rec AND L1-in
        Pack8 ah0[4];
        #pragma unroll
        for (int kk = 0; kk < 4; ++kk)
            ah0[kk].p4 = *(const int4*)(h0r + (rbase + ((kk*64 + 16*g4) ^ swz)));

        if (t < SEQL) {                    // ---- L0 step t ----
            Pack8 xh;
            #pragma unroll
            for (int i = 0; i < 4; ++i) {
                xh.hf[i]     = (_Float16)xa[i];
                xh.hf[4 + i] = (_Float16)xb[i];
            }
            f32x4 acc[4];
            #pragma unroll
            for (int g = 0; g < 4; ++g) {
                float b = biasr0[g];
                acc[g] = (f32x4){b, b, b, b};
            }
            #pragma unroll
            for (int g = 0; g < 4; ++g)
                acc[g] = __builtin_amdgcn_mfma_f32_16x16x32_f16(xh.h, xWf[g].h, acc[g], 0, 0, 0);
            #pragma unroll
            for (int kk = 0; kk < 4; ++kk)
                #pragma unroll
                for (int g = 0; g < 4; ++g)
                    acc[g] = __builtin_amdgcn_mfma_f32_16x16x32_f16(ah0[kk].h, recW0f[g][kk].h, acc[g], 0, 0, 0);

            // prefetch x(t+1)
            int tn = (t + 1 < SEQL) ? t + 1 : t;
            const float* pn = xp + (size_t)tn * 32;
            xa = *(const f32x4*)(pn);
            xb = *(const f32x4*)(pn + 4);

            #pragma unroll
            for (int r = 0; r < 4; ++r) {
                float gi = fsig(acc[0][r]);
                float gf = fsig(acc[1][r]);
                float gg = ftanh(acc[2][r]);
                float go = fsig(acc[3][r]);
                float cc = gf * cst0[r] + gi * gg;
                cst0[r] = cc;
                float hh = go * ftanh(cc);
                *(_Float16*)(h0w + woff[r]) = (_Float16)hh;
            }
        }

        if (t >= 1) {                      // ---- L1 step t-1 ----
            Pack8 ah1[4];
            #pragma unroll
            for (int kk = 0; kk < 4; ++kk)
                ah1[kk].p4 = *(const int4*)(h1r + (rbase + ((kk*64 + 16*g4) ^ swz)));

            f32x4 acc[4];
            #pragma unroll
            for (int g = 0; g < 4; ++g) {
                float b = biasr1[g];
                acc[g] = (f32x4){b, b, b, b};
            }
            // input term: B-frags streamed from LDS (offset is compile-time imm)
            #pragma unroll
            for (int kk = 0; kk < 4; ++kk)
                #pragma unroll
                for (int g = 0; g < 4; ++g) {
                    Pack8 bB;
                    bB.p4 = *(const int4*)(smem + inBbase + (g*4 + kk)*1024 + lane*16);
                    acc[g] = __builtin_amdgcn_mfma_f32_16x16x32_f16(ah0[kk].h, bB.h, acc[g], 0, 0, 0);
                }
            #pragma unroll
            for (int kk = 0; kk < 4; ++kk)
                #pragma unroll
                for (int g = 0; g < 4; ++g)
                    acc[g] = __builtin_amdgcn_mfma_f32_16x16x32_f16(ah1[kk].h, recW1f[g][kk].h, acc[g], 0, 0, 0);

            if (t == SEQL) {
                // all inL reads are done (ds_reads drained before MFMA use);
                // barrier, then reuse smem base for lastH
                __syncthreads();
                float* lastH = (float*)smem;
                #pragma unroll
                for (int r = 0; r < 4; ++r) {
                    float gi = fsig(acc[0][r]);
                    float gf = fsig(acc[1][r]);
                    float gg = ftanh(acc[2][r]);
                    float go = fsig(acc[3][r]);
                    float cc = gf * cst1[r] + gi * gg;
                    float hh = go * ftanh(cc);
                    lastH[(4*g4 + r) * HID + unit] = hh;
                }
            } else {
                #pragma unroll
                for (int r = 0; r < 4; ++r) {
                    float gi = fsig(acc[0][r]);
                    float gf = fsig(acc[1][r]);
                    float gg = ftanh(acc[2][r]);
                    float go = fsig(acc[3][r]);
                    float cc = gf * cst1[r] + gi * gg;
                    cst1[r] = cc;
                    float hh = go * ftanh(cc);
                    *(_Float16*)(h1w + woff[r]) = (_Float16)hh;
                }
            }
        }
        __syncthreads();
    }

    // ---- fused FC head on h2(:,511,:) ----
    float* lastH = (float*)smem;                 // [16][128]
    float* fcb   = (float*)(smem + 8192);        // [16][64]
    #pragma unroll
    for (int s = 0; s < 2; ++s) {
        int task = tid + s * TPB;
        int r = task >> 6, o = task & 63;
        float a = fc1_b[o];
        for (int k = 0; k < HID; ++k) a += lastH[r * HID + k] * fc1_w[o * HID + k];
        fcb[r * 64 + o] = fmaxf(a, 0.f);
    }
    __syncthreads();
    if (tid < MT) {
        float a = fc2_b[0];
        for (int k = 0; k < 64; ++k) a += fcb[tid * 64 + k] * fc2_w[k];
        out[row0 + tid] = a;
    }
}

extern "C" void kernel_launch(void* const* d_in, const int* in_sizes, int n_in,
                              void* d_out, int out_size, void* d_ws, size_t ws_size,
                              hipStream_t stream) {
    const float* x     = (const float*)d_in[0];
    const float* w_ih0 = (const float*)d_in[1];
    const float* w_hh0 = (const float*)d_in[2];
    const float* b_ih0 = (const float*)d_in[3];
    const float* b_hh0 = (const float*)d_in[4];
    const float* w_ih1 = (const float*)d_in[5];
    const float* w_hh1 = (const float*)d_in[6];
    const float* b_ih1 = (const float*)d_in[7];
    const float* b_hh1 = (const float*)d_in[8];
    const float* fc1_w = (const float*)d_in[9];
    const float* fc1_b = (const float*)d_in[10];
    const float* fc2_w = (const float*)d_in[11];
    const float* fc2_b = (const float*)d_in[12];

    char* ws = (char*)d_ws;
    short* recW0 = (short*)(ws);                 // 128 KB
    short* recW1 = (short*)(ws + (128u << 10));  // 128 KB
    short* inW1  = (short*)(ws + (256u << 10));  // 128 KB
    short* xW0   = (short*)(ws + (384u << 10));  //  32 KB
    float* bias0 = (float*)(ws + (416u << 10));  //   2 KB
    float* bias1 = (float*)(ws + (418u << 10));  //   2 KB

    static bool attr_set = false;
    if (!attr_set) {
        hipFuncSetAttribute((const void*)fused_lstm_kernel,
                            hipFuncAttributeMaxDynamicSharedMemorySize, 147456);
        attr_set = true;
    }

    prep_kernel<<<108, 256, 0, stream>>>(w_ih0, w_hh0, b_ih0, b_hh0,
                                         w_ih1, w_hh1, b_ih1, b_hh1,
                                         recW0, recW1, inW1, xW0, bias0, bias1);
    fused_lstm_kernel<<<64, TPB, 147456, stream>>>(x, recW0, recW1, inW1, xW0,
                                                   bias0, bias1,
                                                   fc1_w, fc1_b, fc2_w, fc2_b,
                                                   (float*)d_out);
}